// Round 2
// baseline (132087.451 us; speedup 1.0000x reference)
//
#include <hip/hip_runtime.h>
#include <math.h>

// ---------------------------------------------------------------------------
// R2: batch-grouped persistent GRU.
// 32 groups x 8 blocks; group g owns batch elements [8g, 8g+8).
// Within a group the hidden units are split across the 8 member blocks, so
// each weight load (same address across the 8 batch lanes of a wave) feeds
// 8 FMAs -> L2 weight traffic drops 8x (774 GB -> 97 GB) while all 256 CUs
// stay on compute. Full h vectors are exchanged through global memory with
// device-scope flag sync (monotone counters, parity double-buffered).
// Weights pre-swizzled to [unit][gate(r,z,n)][j] so each thread's 3 gate
// streams are contiguous float4 runs over the reduction dim.
// ---------------------------------------------------------------------------

__device__ __forceinline__ float sigmoidf_(float v) {
    return 1.0f / (1.0f + __expf(-v));
}

// src[(g*H+u)*J + j] -> dst[(u*3+g)*J + j]
__global__ void prep_k(const float* __restrict__ src, float* __restrict__ dst,
                       int H, int J) {
    int idx = blockIdx.x * 256 + threadIdx.x;
    int total = 3 * H * J;
    if (idx < total) {
        int g = idx / (H * J);
        int rem = idx - g * H * J;
        int u = rem / J;
        int j = rem - u * J;
        dst[(u * 3 + g) * J + j] = src[(g * H + u) * J + j];
    }
}

__device__ __forceinline__ void flag_wait1(int* f, int target) {
    if (threadIdx.x == 0) {
        while (__hip_atomic_load(f, __ATOMIC_ACQUIRE, __HIP_MEMORY_SCOPE_AGENT) < target)
            __builtin_amdgcn_s_sleep(1);
    }
    __syncthreads();
}

__device__ __forceinline__ void flag_wait2(int* f0, int t0, int* f1, int t1) {
    if (threadIdx.x == 0) {
        while (__hip_atomic_load(f0, __ATOMIC_ACQUIRE, __HIP_MEMORY_SCOPE_AGENT) < t0)
            __builtin_amdgcn_s_sleep(1);
        while (__hip_atomic_load(f1, __ATOMIC_ACQUIRE, __HIP_MEMORY_SCOPE_AGENT) < t1)
            __builtin_amdgcn_s_sleep(1);
    }
    __syncthreads();
}

// all threads: fence+barrier, then tid0 arrives at the group flag
__device__ __forceinline__ void flag_signal(int* f) {
    __threadfence();
    __syncthreads();
    if (threadIdx.x == 0)
        __hip_atomic_fetch_add(f, 1, __ATOMIC_RELEASE, __HIP_MEMORY_SCOPE_AGENT);
}

// copy 8 rows of J floats from ex (rows contiguous) into LDS rows of stride J+4
__device__ __forceinline__ void stage_rows(float* dst, const float* src, int J) {
    int nf4 = (8 * J) >> 2;
    for (int i = threadIdx.x; i < nf4; i += 256) {
        int idx = i << 2;
        int b = idx / J;
        int j = idx - b * J;
        float4 v = *(const float4*)(src + idx);
        *(float4*)(dst + b * (J + 4) + j) = v;
    }
}

__device__ __forceinline__ void zero_rows(float* dst, int n) {
    for (int i = threadIdx.x; i < n; i += 256) dst[i] = 0.0f;
}

// sr += wR.h, sz += wZ.h, sn += wN.h over NF4 float4 chunks (12 indep chains)
template <int NF4>
__device__ __forceinline__ void gdot3(const float* __restrict__ wR,
                                      const float* __restrict__ wZ,
                                      const float* __restrict__ wN,
                                      const float* h,
                                      float& sr, float& sz, float& sn) {
    const float4* r4 = (const float4*)wR;
    const float4* z4 = (const float4*)wZ;
    const float4* n4 = (const float4*)wN;
    const float4* h4 = (const float4*)h;
    float4 AR = {0.f, 0.f, 0.f, 0.f}, AZ = {0.f, 0.f, 0.f, 0.f}, AN = {0.f, 0.f, 0.f, 0.f};
    #pragma unroll 8
    for (int i = 0; i < NF4; ++i) {
        float4 hv = h4[i];
        float4 a = r4[i];
        float4 c = z4[i];
        float4 d = n4[i];
        AR.x = fmaf(hv.x, a.x, AR.x); AR.y = fmaf(hv.y, a.y, AR.y);
        AR.z = fmaf(hv.z, a.z, AR.z); AR.w = fmaf(hv.w, a.w, AR.w);
        AZ.x = fmaf(hv.x, c.x, AZ.x); AZ.y = fmaf(hv.y, c.y, AZ.y);
        AZ.z = fmaf(hv.z, c.z, AZ.z); AZ.w = fmaf(hv.w, c.w, AZ.w);
        AN.x = fmaf(hv.x, d.x, AN.x); AN.y = fmaf(hv.y, d.y, AN.y);
        AN.z = fmaf(hv.z, d.z, AN.z); AN.w = fmaf(hv.w, d.w, AN.w);
    }
    sr += (AR.x + AR.y) + (AR.z + AR.w);
    sz += (AZ.x + AZ.y) + (AZ.z + AZ.w);
    sn += (AN.x + AN.y) + (AN.z + AN.w);
}

__global__ __launch_bounds__(256) void gru_group_kernel(
    const float* __restrict__ x,
    const float* __restrict__ w_ih1,
    const float* __restrict__ b_ih1, const float* __restrict__ b_hh1,
    const float* __restrict__ b_ih2, const float* __restrict__ b_hh2,
    const float* __restrict__ b_ih3, const float* __restrict__ b_hh3,
    const float* __restrict__ b_ih4, const float* __restrict__ b_hh4,
    const float* __restrict__ wA_hh1,  // [256][3][256]
    const float* __restrict__ wA_ih2,  // [128][3][256]
    const float* __restrict__ wA_hh2,  // [128][3][128]
    const float* __restrict__ wA_ih3,  // [128][3][128]
    const float* __restrict__ wA_hh3,  // [128][3][128]
    const float* __restrict__ wA_ih4,  // [256][3][128]
    const float* __restrict__ wA_hh4,  // [256][3][256]
    const float* __restrict__ w_out, const float* __restrict__ b_out,
    int* __restrict__ flags,   // [32][4] monotone arrive counters
    float* __restrict__ ex,    // [32][12288] h exchange, parity double-buffered
    float* __restrict__ out)   // [256][1024], pre-zeroed; partials atomicAdd'ed
{
    const int tid = threadIdx.x;
    const int B = blockIdx.x;
    // group members co-located per XCD (blockIdx%8 ~ XCD on MI355X; perf-only)
    const int xcd = B & 7, m = B >> 3;
    const int group = xcd * 4 + (m >> 3);
    const int member = m & 7;

    int* gf = flags + group * 4;
    float* gex = ex + group * 12288;
    float* h1ex = gex;           // [2][8][256]
    float* h2ex = gex + 4096;    // [2][8][128]
    float* h3ex = gex + 6144;    // [2][8][128]
    float* h4ex = gex + 8192;    // [2][8][256]

    __shared__ float hin[8 * 260];    // ih input staging (stride J+4)
    __shared__ float hprev[8 * 260];  // hh input staging
    __shared__ float gix[128 * 4];    // L2/L3 j-half partials {r,z,xn,hn}
    __shared__ float part[4][8];      // projection per-wave partials

    for (int t = 0; t < 1024; ++t) {
        const int par = t & 1, parp = par ^ 1;

        // ================= layer 1 (in=1 scalar, H=256, U=32) =================
        flag_wait1(&gf[0], t * 8);
        if (t > 0) stage_rows(hprev, h1ex + parp * 2048, 256);
        else       zero_rows(hprev, 8 * 260);
        __syncthreads();
        {
            const int u_local = tid >> 3, b = tid & 7;
            const int u = member * 32 + u_local;
            const float xv = x[(group * 8 + b) * 1024 + t];
            float sr = b_ih1[u]       + xv * w_ih1[u]       + b_hh1[u];
            float sz = b_ih1[u + 256] + xv * w_ih1[u + 256] + b_hh1[u + 256];
            float xn = b_ih1[u + 512] + xv * w_ih1[u + 512];
            float hn = b_hh1[u + 512];
            const float* wb = wA_hh1 + (size_t)u * 3 * 256;
            gdot3<64>(wb, wb + 256, wb + 512, hprev + b * 260, sr, sz, hn);
            const float r = sigmoidf_(sr);
            const float z = sigmoidf_(sz);
            const float n = tanhf(xn + r * hn);
            const float hnew = (1.f - z) * n + z * hprev[b * 260 + u];
            h1ex[par * 2048 + b * 256 + u] = hnew;
        }
        flag_signal(&gf[0]);

        // ================= layer 2 (in=256, H=128, U=16, j-half split) ========
        flag_wait2(&gf[0], (t + 1) * 8, &gf[1], t * 8);
        stage_rows(hin, h1ex + par * 2048, 256);
        if (t > 0) stage_rows(hprev, h2ex + parp * 1024, 128);
        else       zero_rows(hprev, 8 * 132);
        __syncthreads();
        {
            const int half = tid >> 7, t2 = tid & 127;
            const int u_local = t2 >> 3, b = t2 & 7;
            const int u = member * 16 + u_local;
            float sr = 0.f, sz = 0.f, xn = 0.f, hn = 0.f;
            const float* wi = wA_ih2 + (size_t)u * 3 * 256 + half * 128;
            gdot3<32>(wi, wi + 256, wi + 512, hin + b * 260 + half * 128, sr, sz, xn);
            const float* wh = wA_hh2 + (size_t)u * 3 * 128 + half * 64;
            gdot3<16>(wh, wh + 128, wh + 256, hprev + b * 132 + half * 64, sr, sz, hn);
            if (half) {
                float* g4 = gix + t2 * 4;
                g4[0] = sr; g4[1] = sz; g4[2] = xn; g4[3] = hn;
            }
            __syncthreads();
            if (!half) {
                const float* g4 = gix + t2 * 4;
                sr += g4[0] + b_ih2[u]       + b_hh2[u];
                sz += g4[1] + b_ih2[u + 128] + b_hh2[u + 128];
                xn += g4[2] + b_ih2[u + 256];
                hn += g4[3] + b_hh2[u + 256];
                const float r = sigmoidf_(sr);
                const float z = sigmoidf_(sz);
                const float n = tanhf(xn + r * hn);
                const float hnew = (1.f - z) * n + z * hprev[b * 132 + u];
                h2ex[par * 1024 + b * 128 + u] = hnew;
            }
        }
        flag_signal(&gf[1]);

        // ================= layer 3 (in=128, H=128, U=16, j-half split) ========
        flag_wait2(&gf[1], (t + 1) * 8, &gf[2], t * 8);
        stage_rows(hin, h2ex + par * 1024, 128);
        if (t > 0) stage_rows(hprev, h3ex + parp * 1024, 128);
        else       zero_rows(hprev, 8 * 132);
        __syncthreads();
        {
            const int half = tid >> 7, t2 = tid & 127;
            const int u_local = t2 >> 3, b = t2 & 7;
            const int u = member * 16 + u_local;
            float sr = 0.f, sz = 0.f, xn = 0.f, hn = 0.f;
            const float* wi = wA_ih3 + (size_t)u * 3 * 128 + half * 64;
            gdot3<16>(wi, wi + 128, wi + 256, hin + b * 132 + half * 64, sr, sz, xn);
            const float* wh = wA_hh3 + (size_t)u * 3 * 128 + half * 64;
            gdot3<16>(wh, wh + 128, wh + 256, hprev + b * 132 + half * 64, sr, sz, hn);
            if (half) {
                float* g4 = gix + t2 * 4;
                g4[0] = sr; g4[1] = sz; g4[2] = xn; g4[3] = hn;
            }
            __syncthreads();
            if (!half) {
                const float* g4 = gix + t2 * 4;
                sr += g4[0] + b_ih3[u]       + b_hh3[u];
                sz += g4[1] + b_ih3[u + 128] + b_hh3[u + 128];
                xn += g4[2] + b_ih3[u + 256];
                hn += g4[3] + b_hh3[u + 256];
                const float r = sigmoidf_(sr);
                const float z = sigmoidf_(sz);
                const float n = tanhf(xn + r * hn);
                const float hnew = (1.f - z) * n + z * hprev[b * 132 + u];
                h3ex[par * 1024 + b * 128 + u] = hnew;
            }
        }
        flag_signal(&gf[2]);

        // ================= layer 4 (in=128, H=256, U=32) + projection =========
        flag_wait2(&gf[2], (t + 1) * 8, &gf[3], t * 8);
        stage_rows(hin, h3ex + par * 1024, 128);
        if (t > 0) stage_rows(hprev, h4ex + parp * 2048, 256);
        else       zero_rows(hprev, 8 * 260);
        __syncthreads();
        float proj;
        {
            const int u_local = tid >> 3, b = tid & 7;
            const int u = member * 32 + u_local;
            float sr = b_ih4[u]       + b_hh4[u];
            float sz = b_ih4[u + 256] + b_hh4[u + 256];
            float xn = b_ih4[u + 512];
            float hn = b_hh4[u + 512];
            const float* wi = wA_ih4 + (size_t)u * 3 * 128;
            gdot3<32>(wi, wi + 128, wi + 256, hin + b * 132, sr, sz, xn);
            const float* wh = wA_hh4 + (size_t)u * 3 * 256;
            gdot3<64>(wh, wh + 256, wh + 512, hprev + b * 260, sr, sz, hn);
            const float r = sigmoidf_(sr);
            const float z = sigmoidf_(sz);
            const float n = tanhf(xn + r * hn);
            const float hnew = (1.f - z) * n + z * hprev[b * 260 + u];
            h4ex[par * 2048 + b * 256 + u] = hnew;
            // projection partial: sum w_out[u]*h4 over this wave's 8 units
            float p = w_out[u] * hnew;
            p += __shfl_xor(p, 8, 64);
            p += __shfl_xor(p, 16, 64);
            p += __shfl_xor(p, 32, 64);
            if ((tid & 63) < 8) part[tid >> 6][b] = p;
            proj = 0.f; (void)proj;
        }
        __threadfence();
        __syncthreads();
        if (tid == 0)
            __hip_atomic_fetch_add(&gf[3], 1, __ATOMIC_RELEASE, __HIP_MEMORY_SCOPE_AGENT);
        if (tid < 8) {
            float s = part[0][tid] + part[1][tid] + part[2][tid] + part[3][tid];
            if (member == 0) s += b_out[0];
            atomicAdd(&out[(size_t)(group * 8 + tid) * 1024 + t], s);
        }
    }
}

extern "C" void kernel_launch(void* const* d_in, const int* in_sizes, int n_in,
                              void* d_out, int out_size, void* d_ws, size_t ws_size,
                              hipStream_t stream) {
    const float* x     = (const float*)d_in[0];
    const float* w_ih1 = (const float*)d_in[1];
    const float* w_hh1 = (const float*)d_in[2];
    const float* b_ih1 = (const float*)d_in[3];
    const float* b_hh1 = (const float*)d_in[4];
    const float* w_ih2 = (const float*)d_in[5];
    const float* w_hh2 = (const float*)d_in[6];
    const float* b_ih2 = (const float*)d_in[7];
    const float* b_hh2 = (const float*)d_in[8];
    const float* w_ih3 = (const float*)d_in[9];
    const float* w_hh3 = (const float*)d_in[10];
    const float* b_ih3 = (const float*)d_in[11];
    const float* b_hh3 = (const float*)d_in[12];
    const float* w_ih4 = (const float*)d_in[13];
    const float* w_hh4 = (const float*)d_in[14];
    const float* b_ih4 = (const float*)d_in[15];
    const float* b_hh4 = (const float*)d_in[16];
    const float* w_out = (const float*)d_in[17];
    const float* b_out = (const float*)d_in[18];

    float* ws = (float*)d_ws;
    float* wA_hh1 = ws;                  // 196608
    float* wA_ih2 = wA_hh1 + 196608;     //  98304
    float* wA_hh2 = wA_ih2 + 98304;      //  49152
    float* wA_ih3 = wA_hh2 + 49152;      //  49152
    float* wA_hh3 = wA_ih3 + 49152;      //  49152
    float* wA_ih4 = wA_hh3 + 49152;      //  98304
    float* wA_hh4 = wA_ih4 + 98304;      // 196608
    float* ex     = wA_hh4 + 196608;     // 393216
    int*   flags  = (int*)(ex + 393216); // 128 ints

    hipMemsetAsync(flags, 0, 128 * sizeof(int), stream);
    hipMemsetAsync(d_out, 0, 256 * 1024 * sizeof(float), stream);

    prep_k<<<768, 256, 0, stream>>>(w_hh1, wA_hh1, 256, 256);
    prep_k<<<384, 256, 0, stream>>>(w_ih2, wA_ih2, 128, 256);
    prep_k<<<192, 256, 0, stream>>>(w_hh2, wA_hh2, 128, 128);
    prep_k<<<192, 256, 0, stream>>>(w_ih3, wA_ih3, 128, 128);
    prep_k<<<192, 256, 0, stream>>>(w_hh3, wA_hh3, 128, 128);
    prep_k<<<384, 256, 0, stream>>>(w_ih4, wA_ih4, 256, 128);
    prep_k<<<768, 256, 0, stream>>>(w_hh4, wA_hh4, 256, 256);

    gru_group_kernel<<<256, 256, 0, stream>>>(
        x, w_ih1, b_ih1, b_hh1, b_ih2, b_hh2, b_ih3, b_hh3, b_ih4, b_hh4,
        wA_hh1, wA_ih2, wA_hh2, wA_ih3, wA_hh3, wA_ih4, wA_hh4,
        w_out, b_out, flags, ex, (float*)d_out);
}

// Round 3
// 35395.456 us; speedup vs baseline: 3.7318x; 3.7318x over previous
//
#include <hip/hip_runtime.h>
#include <math.h>

// ---------------------------------------------------------------------------
// R3: R2's batch-grouped structure (32 groups x 8 blocks, unit-split, parity
// double-buffered h exchange) with FENCE-FREE sync.
// R2 post-mortem: __ATOMIC_ACQUIRE polls emitted buffer_inv (L2 invalidate)
// per iteration and __threadfence emitted buffer_wbl2 -> the 2.95MB weight
// set was evicted from L2 every layer of every step (132ms, VALUBusy 4.5%).
// Here ALL cross-WG data moves via RELAXED agent-scope atomics, which bypass
// L1/L2 and complete at the coherent LLC; producer ordering is
// s_waitcnt vmcnt(0) (own stores performed) + __syncthreads + relaxed flag
// add. No fence instructions in the hot loop -> weights stay L2-resident.
// ---------------------------------------------------------------------------

__device__ __forceinline__ float sigmoidf_(float v) {
    return 1.0f / (1.0f + __expf(-v));
}

// src[(g*H+u)*J + j] -> dst[(u*3+g)*J + j]
__global__ void prep_k(const float* __restrict__ src, float* __restrict__ dst,
                       int H, int J) {
    int idx = blockIdx.x * 256 + threadIdx.x;
    int total = 3 * H * J;
    if (idx < total) {
        int g = idx / (H * J);
        int rem = idx - g * H * J;
        int u = rem / J;
        int j = rem - u * J;
        dst[(u * 3 + g) * J + j] = src[(g * H + u) * J + j];
    }
}

// ---- fence-free sync primitives -------------------------------------------

__device__ __forceinline__ int flag_peek(int* f) {
    return __hip_atomic_load(f, __ATOMIC_RELAXED, __HIP_MEMORY_SCOPE_AGENT);
}

__device__ __forceinline__ void flag_wait1(int* f, int target) {
    if (threadIdx.x == 0) {
        while (flag_peek(f) < target) __builtin_amdgcn_s_sleep(1);
    }
    __syncthreads();
    asm volatile("" ::: "memory");
}

__device__ __forceinline__ void flag_wait2(int* f0, int t0, int* f1, int t1) {
    if (threadIdx.x == 0) {
        while (flag_peek(f0) < t0) __builtin_amdgcn_s_sleep(1);
        while (flag_peek(f1) < t1) __builtin_amdgcn_s_sleep(1);
    }
    __syncthreads();
    asm volatile("" ::: "memory");
}

// all threads drain their own exchange stores, barrier, then tid0 arrives
__device__ __forceinline__ void flag_signal(int* f) {
    asm volatile("s_waitcnt vmcnt(0)" ::: "memory");
    __syncthreads();
    if (threadIdx.x == 0)
        __hip_atomic_fetch_add(f, 1, __ATOMIC_RELAXED, __HIP_MEMORY_SCOPE_AGENT);
}

__device__ __forceinline__ void ex_store(float* p, float v) {
    __hip_atomic_store(p, v, __ATOMIC_RELAXED, __HIP_MEMORY_SCOPE_AGENT);
}

__device__ __forceinline__ float ex_load(const float* p) {
    return __hip_atomic_load(p, __ATOMIC_RELAXED, __HIP_MEMORY_SCOPE_AGENT);
}

// copy 8 rows of J floats from ex (rows contiguous, LLC-coherent) into LDS
// rows of stride J+4, via relaxed agent atomic loads (bypass L1/L2).
template <int J>
__device__ __forceinline__ void stage_rows_a(float* dst, const float* src) {
    #pragma unroll
    for (int k = 0; k < (8 * J) / 256; ++k) {
        int i = k * 256 + threadIdx.x;
        int b = i / J;
        int j = i - b * J;
        dst[b * (J + 4) + j] = ex_load(src + i);
    }
}

__device__ __forceinline__ void zero_rows(float* dst, int n) {
    for (int i = threadIdx.x; i < n; i += 256) dst[i] = 0.0f;
}

// sr += wR.h, sz += wZ.h, sn += wN.h over NF4 float4 chunks (12 indep chains)
template <int NF4>
__device__ __forceinline__ void gdot3(const float* __restrict__ wR,
                                      const float* __restrict__ wZ,
                                      const float* __restrict__ wN,
                                      const float* h,
                                      float& sr, float& sz, float& sn) {
    const float4* r4 = (const float4*)wR;
    const float4* z4 = (const float4*)wZ;
    const float4* n4 = (const float4*)wN;
    const float4* h4 = (const float4*)h;
    float4 AR = {0.f, 0.f, 0.f, 0.f}, AZ = {0.f, 0.f, 0.f, 0.f}, AN = {0.f, 0.f, 0.f, 0.f};
    #pragma unroll 8
    for (int i = 0; i < NF4; ++i) {
        float4 hv = h4[i];
        float4 a = r4[i];
        float4 c = z4[i];
        float4 d = n4[i];
        AR.x = fmaf(hv.x, a.x, AR.x); AR.y = fmaf(hv.y, a.y, AR.y);
        AR.z = fmaf(hv.z, a.z, AR.z); AR.w = fmaf(hv.w, a.w, AR.w);
        AZ.x = fmaf(hv.x, c.x, AZ.x); AZ.y = fmaf(hv.y, c.y, AZ.y);
        AZ.z = fmaf(hv.z, c.z, AZ.z); AZ.w = fmaf(hv.w, c.w, AZ.w);
        AN.x = fmaf(hv.x, d.x, AN.x); AN.y = fmaf(hv.y, d.y, AN.y);
        AN.z = fmaf(hv.z, d.z, AN.z); AN.w = fmaf(hv.w, d.w, AN.w);
    }
    sr += (AR.x + AR.y) + (AR.z + AR.w);
    sz += (AZ.x + AZ.y) + (AZ.z + AZ.w);
    sn += (AN.x + AN.y) + (AN.z + AN.w);
}

__global__ __launch_bounds__(256) void gru_group_kernel(
    const float* __restrict__ x,
    const float* __restrict__ w_ih1,
    const float* __restrict__ b_ih1, const float* __restrict__ b_hh1,
    const float* __restrict__ b_ih2, const float* __restrict__ b_hh2,
    const float* __restrict__ b_ih3, const float* __restrict__ b_hh3,
    const float* __restrict__ b_ih4, const float* __restrict__ b_hh4,
    const float* __restrict__ wA_hh1,  // [256][3][256]
    const float* __restrict__ wA_ih2,  // [128][3][256]
    const float* __restrict__ wA_hh2,  // [128][3][128]
    const float* __restrict__ wA_ih3,  // [128][3][128]
    const float* __restrict__ wA_hh3,  // [128][3][128]
    const float* __restrict__ wA_ih4,  // [256][3][128]
    const float* __restrict__ wA_hh4,  // [256][3][256]
    const float* __restrict__ w_out, const float* __restrict__ b_out,
    int* __restrict__ flags,   // [32][4] monotone arrive counters
    float* __restrict__ ex,    // [32][12288] h exchange, parity double-buffered
    float* __restrict__ out)   // [256][1024], pre-zeroed; partials atomicAdd'ed
{
    const int tid = threadIdx.x;
    const int B = blockIdx.x;
    const int xcd = B & 7, m = B >> 3;
    const int group = xcd * 4 + (m >> 3);
    const int member = m & 7;

    int* gf = flags + group * 4;
    float* gex = ex + group * 12288;
    float* h1ex = gex;           // [2][8][256]
    float* h2ex = gex + 4096;    // [2][8][128]
    float* h3ex = gex + 6144;    // [2][8][128]
    float* h4ex = gex + 8192;    // [2][8][256]

    __shared__ float hin[8 * 260];    // ih input staging (stride J+4)
    __shared__ float hprev[8 * 260];  // hh input staging
    __shared__ float gix[128 * 4];    // j-half partials {r,z,xn,hn}
    __shared__ float part[4][8];      // projection per-wave partials

    for (int t = 0; t < 1024; ++t) {
        const int par = t & 1, parp = par ^ 1;

        // ================= layer 1 (in=1 scalar, H=256, U=32) =================
        flag_wait1(&gf[0], t * 8);
        if (t > 0) stage_rows_a<256>(hprev, h1ex + parp * 2048);
        else       zero_rows(hprev, 8 * 260);
        __syncthreads();
        {
            const int u_local = tid >> 3, b = tid & 7;
            const int u = member * 32 + u_local;
            const float xv = x[(group * 8 + b) * 1024 + t];
            float sr = b_ih1[u]       + xv * w_ih1[u]       + b_hh1[u];
            float sz = b_ih1[u + 256] + xv * w_ih1[u + 256] + b_hh1[u + 256];
            float xn = b_ih1[u + 512] + xv * w_ih1[u + 512];
            float hn = b_hh1[u + 512];
            const float* wb = wA_hh1 + (size_t)u * 3 * 256;
            gdot3<64>(wb, wb + 256, wb + 512, hprev + b * 260, sr, sz, hn);
            const float r = sigmoidf_(sr);
            const float z = sigmoidf_(sz);
            const float n = tanhf(xn + r * hn);
            const float hnew = (1.f - z) * n + z * hprev[b * 260 + u];
            ex_store(&h1ex[par * 2048 + b * 256 + u], hnew);
        }
        flag_signal(&gf[0]);

        // ================= layer 2 (in=256, H=128, U=16, j-half split) ========
        flag_wait2(&gf[0], (t + 1) * 8, &gf[1], t * 8);
        stage_rows_a<256>(hin, h1ex + par * 2048);
        if (t > 0) stage_rows_a<128>(hprev, h2ex + parp * 1024);
        else       zero_rows(hprev, 8 * 132);
        __syncthreads();
        {
            const int half = tid >> 7, t2 = tid & 127;
            const int u_local = t2 >> 3, b = t2 & 7;
            const int u = member * 16 + u_local;
            float sr = 0.f, sz = 0.f, xn = 0.f, hn = 0.f;
            const float* wi = wA_ih2 + (size_t)u * 3 * 256 + half * 128;
            gdot3<32>(wi, wi + 256, wi + 512, hin + b * 260 + half * 128, sr, sz, xn);
            const float* wh = wA_hh2 + (size_t)u * 3 * 128 + half * 64;
            gdot3<16>(wh, wh + 128, wh + 256, hprev + b * 132 + half * 64, sr, sz, hn);
            if (half) {
                float* g4 = gix + t2 * 4;
                g4[0] = sr; g4[1] = sz; g4[2] = xn; g4[3] = hn;
            }
            __syncthreads();
            if (!half) {
                const float* g4 = gix + t2 * 4;
                sr += g4[0] + b_ih2[u]       + b_hh2[u];
                sz += g4[1] + b_ih2[u + 128] + b_hh2[u + 128];
                xn += g4[2] + b_ih2[u + 256];
                hn += g4[3] + b_hh2[u + 256];
                const float r = sigmoidf_(sr);
                const float z = sigmoidf_(sz);
                const float n = tanhf(xn + r * hn);
                const float hnew = (1.f - z) * n + z * hprev[b * 132 + u];
                ex_store(&h2ex[par * 1024 + b * 128 + u], hnew);
            }
        }
        flag_signal(&gf[1]);

        // ================= layer 3 (in=128, H=128, U=16, j-half split) ========
        flag_wait2(&gf[1], (t + 1) * 8, &gf[2], t * 8);
        stage_rows_a<128>(hin, h2ex + par * 1024);
        if (t > 0) stage_rows_a<128>(hprev, h3ex + parp * 1024);
        else       zero_rows(hprev, 8 * 132);
        __syncthreads();
        {
            const int half = tid >> 7, t2 = tid & 127;
            const int u_local = t2 >> 3, b = t2 & 7;
            const int u = member * 16 + u_local;
            float sr = 0.f, sz = 0.f, xn = 0.f, hn = 0.f;
            const float* wi = wA_ih3 + (size_t)u * 3 * 128 + half * 64;
            gdot3<16>(wi, wi + 128, wi + 256, hin + b * 132 + half * 64, sr, sz, xn);
            const float* wh = wA_hh3 + (size_t)u * 3 * 128 + half * 64;
            gdot3<16>(wh, wh + 128, wh + 256, hprev + b * 132 + half * 64, sr, sz, hn);
            if (half) {
                float* g4 = gix + t2 * 4;
                g4[0] = sr; g4[1] = sz; g4[2] = xn; g4[3] = hn;
            }
            __syncthreads();
            if (!half) {
                const float* g4 = gix + t2 * 4;
                sr += g4[0] + b_ih3[u]       + b_hh3[u];
                sz += g4[1] + b_ih3[u + 128] + b_hh3[u + 128];
                xn += g4[2] + b_ih3[u + 256];
                hn += g4[3] + b_hh3[u + 256];
                const float r = sigmoidf_(sr);
                const float z = sigmoidf_(sz);
                const float n = tanhf(xn + r * hn);
                const float hnew = (1.f - z) * n + z * hprev[b * 132 + u];
                ex_store(&h3ex[par * 1024 + b * 128 + u], hnew);
            }
        }
        flag_signal(&gf[2]);

        // ================= layer 4 (in=128, H=256, U=32) + projection =========
        flag_wait2(&gf[2], (t + 1) * 8, &gf[3], t * 8);
        stage_rows_a<128>(hin, h3ex + par * 1024);
        if (t > 0) stage_rows_a<256>(hprev, h4ex + parp * 2048);
        else       zero_rows(hprev, 8 * 260);
        __syncthreads();
        {
            const int u_local = tid >> 3, b = tid & 7;
            const int u = member * 32 + u_local;
            float sr = b_ih4[u]       + b_hh4[u];
            float sz = b_ih4[u + 256] + b_hh4[u + 256];
            float xn = b_ih4[u + 512];
            float hn = b_hh4[u + 512];
            const float* wi = wA_ih4 + (size_t)u * 3 * 128;
            gdot3<32>(wi, wi + 128, wi + 256, hin + b * 132, sr, sz, xn);
            const float* wh = wA_hh4 + (size_t)u * 3 * 256;
            gdot3<64>(wh, wh + 256, wh + 512, hprev + b * 260, sr, sz, hn);
            const float r = sigmoidf_(sr);
            const float z = sigmoidf_(sz);
            const float n = tanhf(xn + r * hn);
            const float hnew = (1.f - z) * n + z * hprev[b * 260 + u];
            ex_store(&h4ex[par * 2048 + b * 256 + u], hnew);
            // projection partial: sum w_out[u]*h4 over this wave's units
            float p = w_out[u] * hnew;
            p += __shfl_xor(p, 8, 64);
            p += __shfl_xor(p, 16, 64);
            p += __shfl_xor(p, 32, 64);
            if ((tid & 63) < 8) part[tid >> 6][b] = p;
        }
        flag_signal(&gf[3]);   // drains h4 stores, barriers, tid0 adds
        if (tid < 8) {
            float s = part[0][tid] + part[1][tid] + part[2][tid] + part[3][tid];
            if (member == 0) s += b_out[0];
            atomicAdd(&out[(size_t)(group * 8 + tid) * 1024 + t], s);
        }
    }
}

extern "C" void kernel_launch(void* const* d_in, const int* in_sizes, int n_in,
                              void* d_out, int out_size, void* d_ws, size_t ws_size,
                              hipStream_t stream) {
    const float* x     = (const float*)d_in[0];
    const float* w_ih1 = (const float*)d_in[1];
    const float* w_hh1 = (const float*)d_in[2];
    const float* b_ih1 = (const float*)d_in[3];
    const float* b_hh1 = (const float*)d_in[4];
    const float* w_ih2 = (const float*)d_in[5];
    const float* w_hh2 = (const float*)d_in[6];
    const float* b_ih2 = (const float*)d_in[7];
    const float* b_hh2 = (const float*)d_in[8];
    const float* w_ih3 = (const float*)d_in[9];
    const float* w_hh3 = (const float*)d_in[10];
    const float* b_ih3 = (const float*)d_in[11];
    const float* b_hh3 = (const float*)d_in[12];
    const float* w_ih4 = (const float*)d_in[13];
    const float* w_hh4 = (const float*)d_in[14];
    const float* b_ih4 = (const float*)d_in[15];
    const float* b_hh4 = (const float*)d_in[16];
    const float* w_out = (const float*)d_in[17];
    const float* b_out = (const float*)d_in[18];

    float* ws = (float*)d_ws;
    float* wA_hh1 = ws;                  // 196608
    float* wA_ih2 = wA_hh1 + 196608;     //  98304
    float* wA_hh2 = wA_ih2 + 98304;      //  49152
    float* wA_ih3 = wA_hh2 + 49152;      //  49152
    float* wA_hh3 = wA_ih3 + 49152;      //  49152
    float* wA_ih4 = wA_hh3 + 49152;      //  98304
    float* wA_hh4 = wA_ih4 + 98304;      // 196608
    float* ex     = wA_hh4 + 196608;     // 393216
    int*   flags  = (int*)(ex + 393216); // 128 ints

    hipMemsetAsync(flags, 0, 128 * sizeof(int), stream);
    hipMemsetAsync(d_out, 0, 256 * 1024 * sizeof(float), stream);

    prep_k<<<768, 256, 0, stream>>>(w_hh1, wA_hh1, 256, 256);
    prep_k<<<384, 256, 0, stream>>>(w_ih2, wA_ih2, 128, 256);
    prep_k<<<192, 256, 0, stream>>>(w_hh2, wA_hh2, 128, 128);
    prep_k<<<192, 256, 0, stream>>>(w_ih3, wA_ih3, 128, 128);
    prep_k<<<192, 256, 0, stream>>>(w_hh3, wA_hh3, 128, 128);
    prep_k<<<384, 256, 0, stream>>>(w_ih4, wA_ih4, 256, 128);
    prep_k<<<768, 256, 0, stream>>>(w_hh4, wA_hh4, 256, 256);

    gru_group_kernel<<<256, 256, 0, stream>>>(
        x, w_ih1, b_ih1, b_hh1, b_ih2, b_hh2, b_ih3, b_hh3, b_ih4, b_hh4,
        wA_hh1, wA_ih2, wA_hh2, wA_ih3, wA_hh3, wA_ih4, wA_hh4,
        w_out, b_out, flags, ex, (float*)d_out);
}

// Round 4
// 25551.176 us; speedup vs baseline: 5.1695x; 1.3853x over previous
//
#include <hip/hip_runtime.h>
#include <math.h>

// ---------------------------------------------------------------------------
// R4: LAYER-PIPELINED persistent GRU.
// 4 stages (one per layer) x 64 blocks each = 256 blocks (1/CU).
// Stage layout: 8 unit-slices x 8 batch-groups (32 batch each).
// Cross-stage and peer h-exchange through LLC via relaxed agent atomics
// (R3-proven transport, zero cache-flushing fences in the hot loop).
// Key idea vs R3: sync latency is OFF the critical path — upstream h(t) was
// produced a beat earlier, and peer h(t-1) a full beat earlier (its wait is
// placed AFTER the ih-part compute). Steady-state period = max stage compute
// (~L4, 9.2K cyc) + staging, not 4x(latency+compute) per step.
// Ring depth 4 with ack counters for backpressure (checked only when >4
// beats of drift — normally free). Deadlock-free: every wait's dependency is
// strictly earlier in (t, stage) lexicographic order.
// ---------------------------------------------------------------------------

#define DR 4  // exchange ring depth (power of 2)

__device__ __forceinline__ float sigmoidf_(float v) {
    return 1.0f / (1.0f + __expf(-v));
}

// src[(g*H+u)*J + j] -> dst[(u*3+g)*J + j]   (per-unit gate rows, j contiguous)
__global__ void prep_k(const float* __restrict__ src, float* __restrict__ dst,
                       int H, int J) {
    int idx = blockIdx.x * 256 + threadIdx.x;
    int total = 3 * H * J;
    if (idx < total) {
        int g = idx / (H * J);
        int rem = idx - g * H * J;
        int u = rem / J;
        int j = rem - u * J;
        dst[(u * 3 + g) * J + j] = src[(g * H + u) * J + j];
    }
}

// ---- fence-free LLC primitives (R3-proven) --------------------------------
__device__ __forceinline__ int fpeek(const int* f) {
    return __hip_atomic_load(f, __ATOMIC_RELAXED, __HIP_MEMORY_SCOPE_AGENT);
}
__device__ __forceinline__ void fadd(int* f) {
    __hip_atomic_fetch_add(f, 1, __ATOMIC_RELAXED, __HIP_MEMORY_SCOPE_AGENT);
}
__device__ __forceinline__ void ex_store(float* p, float v) {
    __hip_atomic_store(p, v, __ATOMIC_RELAXED, __HIP_MEMORY_SCOPE_AGENT);
}
__device__ __forceinline__ float ex_load(const float* p) {
    return __hip_atomic_load(p, __ATOMIC_RELAXED, __HIP_MEMORY_SCOPE_AGENT);
}

__device__ __forceinline__ void wait1(int* f, int tgt) {
    if (threadIdx.x == 0) {
        while (fpeek(f) < tgt) __builtin_amdgcn_s_sleep(1);
    }
    __syncthreads();
    asm volatile("" ::: "memory");
}
__device__ __forceinline__ void wait2(int* f0, int t0, int* f1, int t1) {
    if (threadIdx.x == 0) {
        while (fpeek(f0) < t0) __builtin_amdgcn_s_sleep(1);
        while (fpeek(f1) < t1) __builtin_amdgcn_s_sleep(1);
    }
    __syncthreads();
    asm volatile("" ::: "memory");
}
// drain own LLC stores, block barrier, tid0 arrives
__device__ __forceinline__ void signal(int* f) {
    asm volatile("s_waitcnt vmcnt(0)" ::: "memory");
    __syncthreads();
    if (threadIdx.x == 0) fadd(f);
}

// stage 32 rows of J floats (contiguous in ex) into LDS rows of stride J+4
template <int J>
__device__ __forceinline__ void stage32(float* dst, const float* src) {
    constexpr int LJ = (J == 256) ? 8 : 7;
    #pragma unroll
    for (int k = 0; k < (32 * J) / 256; ++k) {
        int i = k * 256 + threadIdx.x;
        int b = i >> LJ;
        int j = i & (J - 1);
        dst[b * (J + 4) + j] = ex_load(src + i);
    }
}
template <int J>
__device__ __forceinline__ void zero32(float* dst) {
    for (int i = threadIdx.x; i < 32 * (J + 4); i += 256) dst[i] = 0.0f;
}

// acc{r,z,c} += w{R,Z,N} . h[row]  for KB batch rows (row = b0 + k*(32/KB)).
// Weights from global (L2-resident stream), h from LDS (broadcast-shared).
template <int KB, int J>
__device__ __forceinline__ void dot3(const float* __restrict__ w3,
                                     const float* __restrict__ hst, int b0,
                                     float* ar, float* az, float* ac) {
    const float4* wr = (const float4*)w3;
    const float4* wz = (const float4*)(w3 + J);
    const float4* wn = (const float4*)(w3 + 2 * J);
    const float* rows[KB];
    #pragma unroll
    for (int k = 0; k < KB; ++k) rows[k] = hst + (b0 + k * (32 / KB)) * (J + 4);
    #pragma unroll 4
    for (int j4 = 0; j4 < J / 4; ++j4) {
        float4 a = wr[j4];
        float4 c = wz[j4];
        float4 d = wn[j4];
        #pragma unroll
        for (int k = 0; k < KB; ++k) {
            float4 hv = *(const float4*)(rows[k] + j4 * 4);
            ar[k] = fmaf(hv.x, a.x, ar[k]); ar[k] = fmaf(hv.y, a.y, ar[k]);
            ar[k] = fmaf(hv.z, a.z, ar[k]); ar[k] = fmaf(hv.w, a.w, ar[k]);
            az[k] = fmaf(hv.x, c.x, az[k]); az[k] = fmaf(hv.y, c.y, az[k]);
            az[k] = fmaf(hv.z, c.z, az[k]); az[k] = fmaf(hv.w, c.w, az[k]);
            ac[k] = fmaf(hv.x, d.x, ac[k]); ac[k] = fmaf(hv.y, d.y, ac[k]);
            ac[k] = fmaf(hv.z, d.z, ac[k]); ac[k] = fmaf(hv.w, d.w, ac[k]);
        }
    }
}

__global__ __launch_bounds__(256) void gru_pipe_kernel(
    const float* __restrict__ x,
    const float* __restrict__ w_ih1,
    const float* __restrict__ b_ih1, const float* __restrict__ b_hh1,
    const float* __restrict__ b_ih2, const float* __restrict__ b_hh2,
    const float* __restrict__ b_ih3, const float* __restrict__ b_hh3,
    const float* __restrict__ b_ih4, const float* __restrict__ b_hh4,
    const float* __restrict__ wA_hh1,  // [256][3][256]
    const float* __restrict__ wA_ih2,  // [128][3][256]
    const float* __restrict__ wA_hh2,  // [128][3][128]
    const float* __restrict__ wA_ih3,  // [128][3][128]
    const float* __restrict__ wA_hh3,  // [128][3][128]
    const float* __restrict__ wA_ih4,  // [256][3][128]
    const float* __restrict__ wA_hh4,  // [256][3][256]
    const float* __restrict__ w_out, const float* __restrict__ b_out,
    int* __restrict__ flags,  // [88] counters, stride 16 ints each
    float* __restrict__ ex,   // rings: h1[4][8][32][256] h2/h3[..][128] h4[..][256]
    float* __restrict__ out)  // [256][1024] pre-zeroed
{
    const int tid = threadIdx.x;
    const int bg = blockIdx.x & 7;   // batch group (32 batch) — XCD-co-located
    const int idx = blockIdx.x >> 3;
    const int s = idx >> 3;          // stage 0..3
    const int us = idx & 7;          // unit slice 0..7

    __shared__ float smem[12544];
    __shared__ float xs[32];
    __shared__ float wsum[4][4][8];

    float* h1ex = ex;                 // 4*8*32*256 = 262144
    float* h2ex = ex + 262144;        // 131072
    float* h3ex = ex + 393216;        // 131072
    float* h4ex = ex + 524288;        // 262144

#define ARR(ss)  (flags + ((ss) * 8 + bg) * 16)
#define ACKP(ss) (flags + (32 + (ss) * 8 + bg) * 16)
#define ACKD(ss) (flags + (64 + (ss) * 8 + bg) * 16)

    if (s == 0) {
        // ---- layer 1: in=1 scalar, H=256, NU=32, KB=4 ----
        const int ul = tid >> 3, b0 = tid & 7;
        const int u = us * 32 + ul;
        const float* wh = wA_hh1 + (size_t)u * 768;
        const float br = b_ih1[u] + b_hh1[u];
        const float bz = b_ih1[u + 256] + b_hh1[u + 256];
        const float bxn = b_ih1[u + 512];
        const float bhn = b_hh1[u + 512];
        const float wir = w_ih1[u], wiz = w_ih1[u + 256], win = w_ih1[u + 512];
        float* hprev = smem;  // [32][260]
        int* fA = ARR(0); int* fP = ACKP(0); int* fD = ACKD(0);
        for (int t = 0; t < 1024; ++t) {
            if (t >= DR) wait2(fP, 8 * (t - DR + 1), fD, 8 * (t - DR + 1));
            if (tid < 32) xs[tid] = x[(size_t)(bg * 32 + tid) * 1024 + t];
            if (t > 0) {
                wait1(fA, 8 * t);
                stage32<256>(hprev, h1ex + (size_t)(((t - 1) & 3) * 8 + bg) * 8192);
                __syncthreads();
                if (tid == 0) fadd(fP);
            } else { zero32<256>(hprev); __syncthreads(); }
            float ar[4], az[4], axn[4], ahn[4];
            #pragma unroll
            for (int k = 0; k < 4; ++k) {
                float xv = xs[b0 + 8 * k];
                ar[k] = br + xv * wir; az[k] = bz + xv * wiz;
                axn[k] = bxn + xv * win; ahn[k] = bhn;
            }
            dot3<4, 256>(wh, hprev, b0, ar, az, ahn);
            float* hout = h1ex + (size_t)((t & 3) * 8 + bg) * 8192;
            #pragma unroll
            for (int k = 0; k < 4; ++k) {
                int b = b0 + 8 * k;
                float hp = hprev[b * 260 + u];
                float r = sigmoidf_(ar[k]);
                float z = sigmoidf_(az[k]);
                float n = tanhf(axn[k] + r * ahn[k]);
                ex_store(hout + b * 256 + u, (1.f - z) * n + z * hp);
            }
            signal(fA);
        }
    } else if (s == 1) {
        // ---- layer 2: in=256, H=128, NU=16, KB=2 ----
        const int ul = tid >> 4, b0 = tid & 15;
        const int u = us * 16 + ul;
        const float* wi = wA_ih2 + (size_t)u * 768;
        const float* wh = wA_hh2 + (size_t)u * 384;
        const float br = b_ih2[u] + b_hh2[u];
        const float bz = b_ih2[u + 128] + b_hh2[u + 128];
        const float bxn = b_ih2[u + 256];
        const float bhn = b_hh2[u + 256];
        float* hin = smem;               // [32][260]
        float* hprev = smem + 32 * 260;  // [32][132]
        int* fAin = ARR(0); int* fA = ARR(1);
        int* fP = ACKP(1); int* fDup = ACKD(0); int* fD = ACKD(1);
        for (int t = 0; t < 1024; ++t) {
            if (t >= DR) wait2(fP, 8 * (t - DR + 1), fD, 8 * (t - DR + 1));
            wait1(fAin, 8 * (t + 1));
            stage32<256>(hin, h1ex + (size_t)((t & 3) * 8 + bg) * 8192);
            __syncthreads();
            if (tid == 0) fadd(fDup);
            float ar[2] = {br, br}, az[2] = {bz, bz};
            float axn[2] = {bxn, bxn}, ahn[2] = {bhn, bhn};
            dot3<2, 256>(wi, hin, b0, ar, az, axn);
            if (t > 0) {
                wait1(fA, 8 * t);
                stage32<128>(hprev, h2ex + (size_t)(((t - 1) & 3) * 8 + bg) * 4096);
                __syncthreads();
                if (tid == 0) fadd(fP);
            } else { zero32<128>(hprev); __syncthreads(); }
            dot3<2, 128>(wh, hprev, b0, ar, az, ahn);
            float* hout = h2ex + (size_t)((t & 3) * 8 + bg) * 4096;
            #pragma unroll
            for (int k = 0; k < 2; ++k) {
                int b = b0 + 16 * k;
                float hp = hprev[b * 132 + u];
                float r = sigmoidf_(ar[k]);
                float z = sigmoidf_(az[k]);
                float n = tanhf(axn[k] + r * ahn[k]);
                ex_store(hout + b * 128 + u, (1.f - z) * n + z * hp);
            }
            signal(fA);
        }
    } else if (s == 2) {
        // ---- layer 3: in=128, H=128, NU=16, KB=2 ----
        const int ul = tid >> 4, b0 = tid & 15;
        const int u = us * 16 + ul;
        const float* wi = wA_ih3 + (size_t)u * 384;
        const float* wh = wA_hh3 + (size_t)u * 384;
        const float br = b_ih3[u] + b_hh3[u];
        const float bz = b_ih3[u + 128] + b_hh3[u + 128];
        const float bxn = b_ih3[u + 256];
        const float bhn = b_hh3[u + 256];
        float* hin = smem;               // [32][132]
        float* hprev = smem + 32 * 132;  // [32][132]
        int* fAin = ARR(1); int* fA = ARR(2);
        int* fP = ACKP(2); int* fDup = ACKD(1); int* fD = ACKD(2);
        for (int t = 0; t < 1024; ++t) {
            if (t >= DR) wait2(fP, 8 * (t - DR + 1), fD, 8 * (t - DR + 1));
            wait1(fAin, 8 * (t + 1));
            stage32<128>(hin, h2ex + (size_t)((t & 3) * 8 + bg) * 4096);
            __syncthreads();
            if (tid == 0) fadd(fDup);
            float ar[2] = {br, br}, az[2] = {bz, bz};
            float axn[2] = {bxn, bxn}, ahn[2] = {bhn, bhn};
            dot3<2, 128>(wi, hin, b0, ar, az, axn);
            if (t > 0) {
                wait1(fA, 8 * t);
                stage32<128>(hprev, h3ex + (size_t)(((t - 1) & 3) * 8 + bg) * 4096);
                __syncthreads();
                if (tid == 0) fadd(fP);
            } else { zero32<128>(hprev); __syncthreads(); }
            dot3<2, 128>(wh, hprev, b0, ar, az, ahn);
            float* hout = h3ex + (size_t)((t & 3) * 8 + bg) * 4096;
            #pragma unroll
            for (int k = 0; k < 2; ++k) {
                int b = b0 + 16 * k;
                float hp = hprev[b * 132 + u];
                float r = sigmoidf_(ar[k]);
                float z = sigmoidf_(az[k]);
                float n = tanhf(axn[k] + r * ahn[k]);
                ex_store(hout + b * 128 + u, (1.f - z) * n + z * hp);
            }
            signal(fA);
        }
    } else {
        // ---- layer 4: in=128, H=256, NU=32, KB=4, + output projection ----
        const int ul = tid >> 3, b0 = tid & 7;
        const int u = us * 32 + ul;
        const float* wi = wA_ih4 + (size_t)u * 384;
        const float* wh = wA_hh4 + (size_t)u * 768;
        const float br = b_ih4[u] + b_hh4[u];
        const float bz = b_ih4[u + 256] + b_hh4[u + 256];
        const float bxn = b_ih4[u + 512];
        const float bhn = b_hh4[u + 512];
        const float wo = w_out[u];
        float* hin = smem;               // [32][132]
        float* hprev = smem + 32 * 132;  // [32][260]
        int* fAin = ARR(2); int* fA = ARR(3);
        int* fP = ACKP(3); int* fDup = ACKD(2);
        for (int t = 0; t < 1024; ++t) {
            if (t >= DR) wait1(fP, 8 * (t - DR + 1));
            wait1(fAin, 8 * (t + 1));
            stage32<128>(hin, h3ex + (size_t)((t & 3) * 8 + bg) * 4096);
            __syncthreads();
            if (tid == 0) fadd(fDup);
            float ar[4], az[4], axn[4], ahn[4];
            #pragma unroll
            for (int k = 0; k < 4; ++k) {
                ar[k] = br; az[k] = bz; axn[k] = bxn; ahn[k] = bhn;
            }
            dot3<4, 128>(wi, hin, b0, ar, az, axn);
            if (t > 0) {
                wait1(fA, 8 * t);
                stage32<256>(hprev, h4ex + (size_t)(((t - 1) & 3) * 8 + bg) * 8192);
                __syncthreads();
                if (tid == 0) fadd(fP);
            } else { zero32<256>(hprev); __syncthreads(); }
            dot3<4, 256>(wh, hprev, b0, ar, az, ahn);
            float* hout = h4ex + (size_t)((t & 3) * 8 + bg) * 8192;
            float pk[4];
            #pragma unroll
            for (int k = 0; k < 4; ++k) {
                int b = b0 + 8 * k;
                float hp = hprev[b * 260 + u];
                float r = sigmoidf_(ar[k]);
                float z = sigmoidf_(az[k]);
                float n = tanhf(axn[k] + r * ahn[k]);
                float hnew = (1.f - z) * n + z * hp;
                ex_store(hout + b * 256 + u, hnew);
                pk[k] = wo * hnew;
            }
            // reduce over the wave's 8 unit-lanes (lane bits 3..5)
            #pragma unroll
            for (int k = 0; k < 4; ++k) {
                pk[k] += __shfl_xor(pk[k], 8, 64);
                pk[k] += __shfl_xor(pk[k], 16, 64);
                pk[k] += __shfl_xor(pk[k], 32, 64);
            }
            if ((tid & 63) < 8) {
                int w = tid >> 6;
                #pragma unroll
                for (int k = 0; k < 4; ++k) wsum[w][k][tid & 7] = pk[k];
            }
            signal(fA);  // barrier inside makes wsum visible
            if (tid < 32) {
                int k = tid >> 3, bb = tid & 7;
                float ssum = wsum[0][k][bb] + wsum[1][k][bb] +
                             wsum[2][k][bb] + wsum[3][k][bb];
                if (us == 0) ssum += b_out[0];
                atomicAdd(out + (size_t)(bg * 32 + bb + 8 * k) * 1024 + t, ssum);
            }
        }
    }
#undef ARR
#undef ACKP
#undef ACKD
}

extern "C" void kernel_launch(void* const* d_in, const int* in_sizes, int n_in,
                              void* d_out, int out_size, void* d_ws, size_t ws_size,
                              hipStream_t stream) {
    const float* x     = (const float*)d_in[0];
    const float* w_ih1 = (const float*)d_in[1];
    const float* w_hh1 = (const float*)d_in[2];
    const float* b_ih1 = (const float*)d_in[3];
    const float* b_hh1 = (const float*)d_in[4];
    const float* w_ih2 = (const float*)d_in[5];
    const float* w_hh2 = (const float*)d_in[6];
    const float* b_ih2 = (const float*)d_in[7];
    const float* b_hh2 = (const float*)d_in[8];
    const float* w_ih3 = (const float*)d_in[9];
    const float* w_hh3 = (const float*)d_in[10];
    const float* b_ih3 = (const float*)d_in[11];
    const float* b_hh3 = (const float*)d_in[12];
    const float* w_ih4 = (const float*)d_in[13];
    const float* w_hh4 = (const float*)d_in[14];
    const float* b_ih4 = (const float*)d_in[15];
    const float* b_hh4 = (const float*)d_in[16];
    const float* w_out = (const float*)d_in[17];
    const float* b_out = (const float*)d_in[18];

    float* ws = (float*)d_ws;
    float* wA_hh1 = ws;                  // 196608
    float* wA_ih2 = wA_hh1 + 196608;     //  98304
    float* wA_hh2 = wA_ih2 + 98304;      //  49152
    float* wA_ih3 = wA_hh2 + 49152;      //  49152
    float* wA_hh3 = wA_ih3 + 49152;      //  49152
    float* wA_ih4 = wA_hh3 + 49152;      //  98304
    float* wA_hh4 = wA_ih4 + 98304;      // 196608
    float* ex     = wA_hh4 + 196608;     // 786432 (h rings)
    int*   flags  = (int*)(ex + 786432); // 88*16 ints

    hipMemsetAsync(flags, 0, 88 * 16 * sizeof(int), stream);
    hipMemsetAsync(d_out, 0, 256 * 1024 * sizeof(float), stream);

    prep_k<<<768, 256, 0, stream>>>(w_hh1, wA_hh1, 256, 256);
    prep_k<<<384, 256, 0, stream>>>(w_ih2, wA_ih2, 128, 256);
    prep_k<<<192, 256, 0, stream>>>(w_hh2, wA_hh2, 128, 128);
    prep_k<<<192, 256, 0, stream>>>(w_ih3, wA_ih3, 128, 128);
    prep_k<<<192, 256, 0, stream>>>(w_hh3, wA_hh3, 128, 128);
    prep_k<<<384, 256, 0, stream>>>(w_ih4, wA_ih4, 256, 128);
    prep_k<<<768, 256, 0, stream>>>(w_hh4, wA_hh4, 256, 256);

    gru_pipe_kernel<<<256, 256, 0, stream>>>(
        x, w_ih1, b_ih1, b_hh1, b_ih2, b_hh2, b_ih3, b_hh3, b_ih4, b_hh4,
        wA_hh1, wA_ih2, wA_hh2, wA_ih3, wA_hh3, wA_ih4, wA_hh4,
        w_out, b_out, flags, ex, (float*)d_out);
}

// Round 5
// 24769.405 us; speedup vs baseline: 5.3327x; 1.0316x over previous
//
#include <hip/hip_runtime.h>
#include <math.h>

// ---------------------------------------------------------------------------
// R5: R4's 4-stage layer pipeline + LDS-RESIDENT hh WEIGHTS.
// R4 post-mortem: the 25us beat was dominated by re-streaming the hh weight
// slice from L2 inside the serial recurrence cycle (~200cyc L2 latency, only
// ~12 loads in flight, 1 block/CU). hh slices are 24-96KB/block -> load once
// into LDS in a prologue; the recurrence-critical dot becomes pure LDS+FMA.
// ih weights (stages 2-4) stay L2-streamed: they're on the pipelined side.
// Sync protocol identical to R4 (relaxed-LLC flags, ring depth 4, acks).
// LDS: L4 needs 37248 floats (~149KB) -> dynamic LDS + hipFuncSetAttribute.
// Bank layout: weight rows padded to 772/388 floats (stride = 4 mod 32) so
// the 4-8 unit rows in a wave spread across banks; batch-lane weight reads
// are same-address broadcast (free); h rows stride 260/132 = 4 mod 32 ->
// worst 2-way conflict (free per m136).
// ---------------------------------------------------------------------------

#define DR 4  // exchange ring depth

__device__ __forceinline__ float sigmoidf_(float v) {
    return 1.0f / (1.0f + __expf(-v));
}

// src[(g*H+u)*J + j] -> dst[(u*3+g)*J + j]   (per-unit gate rows, j contiguous)
__global__ void prep_k(const float* __restrict__ src, float* __restrict__ dst,
                       int H, int J) {
    int idx = blockIdx.x * 256 + threadIdx.x;
    int total = 3 * H * J;
    if (idx < total) {
        int g = idx / (H * J);
        int rem = idx - g * H * J;
        int u = rem / J;
        int j = rem - u * J;
        dst[(u * 3 + g) * J + j] = src[(g * H + u) * J + j];
    }
}

// ---- fence-free LLC primitives (R3-proven) --------------------------------
__device__ __forceinline__ int fpeek(const int* f) {
    return __hip_atomic_load(f, __ATOMIC_RELAXED, __HIP_MEMORY_SCOPE_AGENT);
}
__device__ __forceinline__ void fadd(int* f) {
    __hip_atomic_fetch_add(f, 1, __ATOMIC_RELAXED, __HIP_MEMORY_SCOPE_AGENT);
}
__device__ __forceinline__ void ex_store(float* p, float v) {
    __hip_atomic_store(p, v, __ATOMIC_RELAXED, __HIP_MEMORY_SCOPE_AGENT);
}
__device__ __forceinline__ float ex_load(const float* p) {
    return __hip_atomic_load(p, __ATOMIC_RELAXED, __HIP_MEMORY_SCOPE_AGENT);
}

__device__ __forceinline__ void wait1(int* f, int tgt) {
    if (threadIdx.x == 0) {
        while (fpeek(f) < tgt) __builtin_amdgcn_s_sleep(1);
    }
    __syncthreads();
    asm volatile("" ::: "memory");
}
__device__ __forceinline__ void wait2(int* f0, int t0, int* f1, int t1) {
    if (threadIdx.x == 0) {
        while (fpeek(f0) < t0) __builtin_amdgcn_s_sleep(1);
        while (fpeek(f1) < t1) __builtin_amdgcn_s_sleep(1);
    }
    __syncthreads();
    asm volatile("" ::: "memory");
}
// drain own LLC stores, block barrier, tid0 arrives
__device__ __forceinline__ void signal(int* f) {
    asm volatile("s_waitcnt vmcnt(0)" ::: "memory");
    __syncthreads();
    if (threadIdx.x == 0) fadd(f);
}

// stage 32 rows of J floats (contiguous in ex) into LDS rows of stride J+4
template <int J>
__device__ __forceinline__ void stage32(float* dst, const float* src) {
    constexpr int LJ = (J == 256) ? 8 : 7;
    #pragma unroll
    for (int k = 0; k < (32 * J) / 256; ++k) {
        int i = k * 256 + threadIdx.x;
        int b = i >> LJ;
        int j = i & (J - 1);
        dst[b * (J + 4) + j] = ex_load(src + i);
    }
}
template <int J>
__device__ __forceinline__ void zero32(float* dst) {
    for (int i = threadIdx.x; i < 32 * (J + 4); i += 256) dst[i] = 0.0f;
}

// acc{r,z,c} += w{R,Z,N} . h[row]  for KB batch rows (row = b0 + k*(32/KB)).
// w3 may point to global (L2 stream, ih side) or LDS (hh side) — inlining
// specializes the address space per call site.
template <int KB, int J>
__device__ __forceinline__ void dot3(const float* __restrict__ w3,
                                     const float* __restrict__ hst, int b0,
                                     float* ar, float* az, float* ac) {
    const float4* wr = (const float4*)w3;
    const float4* wz = (const float4*)(w3 + J);
    const float4* wn = (const float4*)(w3 + 2 * J);
    const float* rows[KB];
    #pragma unroll
    for (int k = 0; k < KB; ++k) rows[k] = hst + (b0 + k * (32 / KB)) * (J + 4);
    #pragma unroll 4
    for (int j4 = 0; j4 < J / 4; ++j4) {
        float4 a = wr[j4];
        float4 c = wz[j4];
        float4 d = wn[j4];
        #pragma unroll
        for (int k = 0; k < KB; ++k) {
            float4 hv = *(const float4*)(rows[k] + j4 * 4);
            ar[k] = fmaf(hv.x, a.x, ar[k]); ar[k] = fmaf(hv.y, a.y, ar[k]);
            ar[k] = fmaf(hv.z, a.z, ar[k]); ar[k] = fmaf(hv.w, a.w, ar[k]);
            az[k] = fmaf(hv.x, c.x, az[k]); az[k] = fmaf(hv.y, c.y, az[k]);
            az[k] = fmaf(hv.z, c.z, az[k]); az[k] = fmaf(hv.w, c.w, az[k]);
            ac[k] = fmaf(hv.x, d.x, ac[k]); ac[k] = fmaf(hv.y, d.y, ac[k]);
            ac[k] = fmaf(hv.z, d.z, ac[k]); ac[k] = fmaf(hv.w, d.w, ac[k]);
        }
    }
}

__global__ __launch_bounds__(256) void gru_pipe_kernel(
    const float* __restrict__ x,
    const float* __restrict__ w_ih1,
    const float* __restrict__ b_ih1, const float* __restrict__ b_hh1,
    const float* __restrict__ b_ih2, const float* __restrict__ b_hh2,
    const float* __restrict__ b_ih3, const float* __restrict__ b_hh3,
    const float* __restrict__ b_ih4, const float* __restrict__ b_hh4,
    const float* __restrict__ wA_hh1,  // [256][3][256]
    const float* __restrict__ wA_ih2,  // [128][3][256]
    const float* __restrict__ wA_hh2,  // [128][3][128]
    const float* __restrict__ wA_ih3,  // [128][3][128]
    const float* __restrict__ wA_hh3,  // [128][3][128]
    const float* __restrict__ wA_ih4,  // [256][3][128]
    const float* __restrict__ wA_hh4,  // [256][3][256]
    const float* __restrict__ w_out, const float* __restrict__ b_out,
    int* __restrict__ flags,  // counters, stride 16 ints
    float* __restrict__ ex,   // rings: h1[4][8][32][256] h2/h3[..][128] h4[..][256]
    float* __restrict__ out)  // [256][1024] pre-zeroed
{
    const int tid = threadIdx.x;
    const int bg = blockIdx.x & 7;   // batch group (32 rows)
    const int idx = blockIdx.x >> 3;
    const int s = idx >> 3;          // stage 0..3
    const int us = idx & 7;          // unit slice 0..7

    extern __shared__ float smem[];
    __shared__ float xs[32];
    __shared__ float wsum[4][4][8];

    float* h1ex = ex;                 // 4*8*32*256 = 262144
    float* h2ex = ex + 262144;        // 131072
    float* h3ex = ex + 393216;        // 131072
    float* h4ex = ex + 524288;        // 262144

#define ARR(ss)  (flags + ((ss) * 8 + bg) * 16)
#define ACKP(ss) (flags + (32 + (ss) * 8 + bg) * 16)
#define ACKD(ss) (flags + (64 + (ss) * 8 + bg) * 16)

    if (s == 0) {
        // ---- layer 1: in=1 scalar, H=256, NU=32, KB=4, hh in LDS ----
        const int ul = tid >> 3, b0 = tid & 7;
        const int u = us * 32 + ul;
        float* wlds = smem;              // [32][772] (3*256 + 4 pad)
        float* hprev = smem + 24704;     // [32][260]
        {   // prologue: hh slice -> LDS
            const float* src = wA_hh1 + (size_t)us * 32 * 768;
            for (int i = tid; i < 24576; i += 256) {
                int uu = i / 768, r = i - uu * 768;
                wlds[uu * 772 + r] = src[i];
            }
        }
        __syncthreads();
        const float* wh = wlds + ul * 772;
        const float br = b_ih1[u] + b_hh1[u];
        const float bz = b_ih1[u + 256] + b_hh1[u + 256];
        const float bxn = b_ih1[u + 512];
        const float bhn = b_hh1[u + 512];
        const float wir = w_ih1[u], wiz = w_ih1[u + 256], win = w_ih1[u + 512];
        int* fA = ARR(0); int* fP = ACKP(0); int* fD = ACKD(0);
        for (int t = 0; t < 1024; ++t) {
            if (t >= DR) wait2(fP, 8 * (t - DR + 1), fD, 8 * (t - DR + 1));
            if (tid < 32) xs[tid] = x[(size_t)(bg * 32 + tid) * 1024 + t];
            if (t > 0) {
                wait1(fA, 8 * t);
                stage32<256>(hprev, h1ex + (size_t)(((t - 1) & 3) * 8 + bg) * 8192);
                __syncthreads();
                if (tid == 0) fadd(fP);
            } else { zero32<256>(hprev); __syncthreads(); }
            float ar[4], az[4], axn[4], ahn[4];
            #pragma unroll
            for (int k = 0; k < 4; ++k) {
                float xv = xs[b0 + 8 * k];
                ar[k] = br + xv * wir; az[k] = bz + xv * wiz;
                axn[k] = bxn + xv * win; ahn[k] = bhn;
            }
            dot3<4, 256>(wh, hprev, b0, ar, az, ahn);
            float* hout = h1ex + (size_t)((t & 3) * 8 + bg) * 8192;
            #pragma unroll
            for (int k = 0; k < 4; ++k) {
                int b = b0 + 8 * k;
                float hp = hprev[b * 260 + u];
                float r = sigmoidf_(ar[k]);
                float z = sigmoidf_(az[k]);
                float n = tanhf(axn[k] + r * ahn[k]);
                ex_store(hout + b * 256 + u, (1.f - z) * n + z * hp);
            }
            signal(fA);
        }
    } else if (s == 1) {
        // ---- layer 2: in=256, H=128, NU=16, KB=2, hh in LDS ----
        const int ul = tid >> 4, b0 = tid & 15;
        const int u = us * 16 + ul;
        float* wlds = smem;              // [16][388]
        float* hin = smem + 6208;        // [32][260]
        float* hprev = hin + 8320;       // [32][132]
        {
            const float* src = wA_hh2 + (size_t)us * 16 * 384;
            for (int i = tid; i < 6144; i += 256) {
                int uu = i / 384, r = i - uu * 384;
                wlds[uu * 388 + r] = src[i];
            }
        }
        __syncthreads();
        const float* wi = wA_ih2 + (size_t)u * 768;
        const float* wh = wlds + ul * 388;
        const float br = b_ih2[u] + b_hh2[u];
        const float bz = b_ih2[u + 128] + b_hh2[u + 128];
        const float bxn = b_ih2[u + 256];
        const float bhn = b_hh2[u + 256];
        int* fAin = ARR(0); int* fA = ARR(1);
        int* fP = ACKP(1); int* fDup = ACKD(0); int* fD = ACKD(1);
        for (int t = 0; t < 1024; ++t) {
            if (t >= DR) wait2(fP, 8 * (t - DR + 1), fD, 8 * (t - DR + 1));
            wait1(fAin, 8 * (t + 1));
            stage32<256>(hin, h1ex + (size_t)((t & 3) * 8 + bg) * 8192);
            __syncthreads();
            if (tid == 0) fadd(fDup);
            float ar[2] = {br, br}, az[2] = {bz, bz};
            float axn[2] = {bxn, bxn}, ahn[2] = {bhn, bhn};
            dot3<2, 256>(wi, hin, b0, ar, az, axn);
            if (t > 0) {
                wait1(fA, 8 * t);
                stage32<128>(hprev, h2ex + (size_t)(((t - 1) & 3) * 8 + bg) * 4096);
                __syncthreads();
                if (tid == 0) fadd(fP);
            } else { zero32<128>(hprev); __syncthreads(); }
            dot3<2, 128>(wh, hprev, b0, ar, az, ahn);
            float* hout = h2ex + (size_t)((t & 3) * 8 + bg) * 4096;
            #pragma unroll
            for (int k = 0; k < 2; ++k) {
                int b = b0 + 16 * k;
                float hp = hprev[b * 132 + u];
                float r = sigmoidf_(ar[k]);
                float z = sigmoidf_(az[k]);
                float n = tanhf(axn[k] + r * ahn[k]);
                ex_store(hout + b * 128 + u, (1.f - z) * n + z * hp);
            }
            signal(fA);
        }
    } else if (s == 2) {
        // ---- layer 3: in=128, H=128, NU=16, KB=2, hh in LDS ----
        const int ul = tid >> 4, b0 = tid & 15;
        const int u = us * 16 + ul;
        float* wlds = smem;              // [16][388]
        float* hin = smem + 6208;        // [32][132]
        float* hprev = hin + 4224;       // [32][132]
        {
            const float* src = wA_hh3 + (size_t)us * 16 * 384;
            for (int i = tid; i < 6144; i += 256) {
                int uu = i / 384, r = i - uu * 384;
                wlds[uu * 388 + r] = src[i];
            }
        }
        __syncthreads();
        const float* wi = wA_ih3 + (size_t)u * 384;
        const float* wh = wlds + ul * 388;
        const float br = b_ih3[u] + b_hh3[u];
        const float bz = b_ih3[u + 128] + b_hh3[u + 128];
        const float bxn = b_ih3[u + 256];
        const float bhn = b_hh3[u + 256];
        int* fAin = ARR(1); int* fA = ARR(2);
        int* fP = ACKP(2); int* fDup = ACKD(1); int* fD = ACKD(2);
        for (int t = 0; t < 1024; ++t) {
            if (t >= DR) wait2(fP, 8 * (t - DR + 1), fD, 8 * (t - DR + 1));
            wait1(fAin, 8 * (t + 1));
            stage32<128>(hin, h2ex + (size_t)((t & 3) * 8 + bg) * 4096);
            __syncthreads();
            if (tid == 0) fadd(fDup);
            float ar[2] = {br, br}, az[2] = {bz, bz};
            float axn[2] = {bxn, bxn}, ahn[2] = {bhn, bhn};
            dot3<2, 128>(wi, hin, b0, ar, az, axn);
            if (t > 0) {
                wait1(fA, 8 * t);
                stage32<128>(hprev, h3ex + (size_t)(((t - 1) & 3) * 8 + bg) * 4096);
                __syncthreads();
                if (tid == 0) fadd(fP);
            } else { zero32<128>(hprev); __syncthreads(); }
            dot3<2, 128>(wh, hprev, b0, ar, az, ahn);
            float* hout = h3ex + (size_t)((t & 3) * 8 + bg) * 4096;
            #pragma unroll
            for (int k = 0; k < 2; ++k) {
                int b = b0 + 16 * k;
                float hp = hprev[b * 132 + u];
                float r = sigmoidf_(ar[k]);
                float z = sigmoidf_(az[k]);
                float n = tanhf(axn[k] + r * ahn[k]);
                ex_store(hout + b * 128 + u, (1.f - z) * n + z * hp);
            }
            signal(fA);
        }
    } else {
        // ---- layer 4: in=128, H=256, NU=32, KB=4, hh in LDS, + projection ----
        const int ul = tid >> 3, b0 = tid & 7;
        const int u = us * 32 + ul;
        float* wlds = smem;              // [32][772]
        float* hin = smem + 24704;       // [32][132]
        float* hprev = hin + 4224;       // [32][260]
        {
            const float* src = wA_hh4 + (size_t)us * 32 * 768;
            for (int i = tid; i < 24576; i += 256) {
                int uu = i / 768, r = i - uu * 768;
                wlds[uu * 772 + r] = src[i];
            }
        }
        __syncthreads();
        const float* wi = wA_ih4 + (size_t)u * 384;
        const float* wh = wlds + ul * 772;
        const float br = b_ih4[u] + b_hh4[u];
        const float bz = b_ih4[u + 256] + b_hh4[u + 256];
        const float bxn = b_ih4[u + 512];
        const float bhn = b_hh4[u + 512];
        const float wo = w_out[u];
        int* fAin = ARR(2); int* fA = ARR(3);
        int* fP = ACKP(3); int* fDup = ACKD(2);
        for (int t = 0; t < 1024; ++t) {
            if (t >= DR) wait1(fP, 8 * (t - DR + 1));
            wait1(fAin, 8 * (t + 1));
            stage32<128>(hin, h3ex + (size_t)((t & 3) * 8 + bg) * 4096);
            __syncthreads();
            if (tid == 0) fadd(fDup);
            float ar[4], az[4], axn[4], ahn[4];
            #pragma unroll
            for (int k = 0; k < 4; ++k) {
                ar[k] = br; az[k] = bz; axn[k] = bxn; ahn[k] = bhn;
            }
            dot3<4, 128>(wi, hin, b0, ar, az, axn);
            if (t > 0) {
                wait1(fA, 8 * t);
                stage32<256>(hprev, h4ex + (size_t)(((t - 1) & 3) * 8 + bg) * 8192);
                __syncthreads();
                if (tid == 0) fadd(fP);
            } else { zero32<256>(hprev); __syncthreads(); }
            dot3<4, 256>(wh, hprev, b0, ar, az, ahn);
            float* hout = h4ex + (size_t)((t & 3) * 8 + bg) * 8192;
            float pk[4];
            #pragma unroll
            for (int k = 0; k < 4; ++k) {
                int b = b0 + 8 * k;
                float hp = hprev[b * 260 + u];
                float r = sigmoidf_(ar[k]);
                float z = sigmoidf_(az[k]);
                float n = tanhf(axn[k] + r * ahn[k]);
                float hnew = (1.f - z) * n + z * hp;
                ex_store(hout + b * 256 + u, hnew);
                pk[k] = wo * hnew;
            }
            #pragma unroll
            for (int k = 0; k < 4; ++k) {
                pk[k] += __shfl_xor(pk[k], 8, 64);
                pk[k] += __shfl_xor(pk[k], 16, 64);
                pk[k] += __shfl_xor(pk[k], 32, 64);
            }
            if ((tid & 63) < 8) {
                int w = tid >> 6;
                #pragma unroll
                for (int k = 0; k < 4; ++k) wsum[w][k][tid & 7] = pk[k];
            }
            signal(fA);  // barrier inside makes wsum visible
            if (tid < 32) {
                int k = tid >> 3, bb = tid & 7;
                float ssum = wsum[0][k][bb] + wsum[1][k][bb] +
                             wsum[2][k][bb] + wsum[3][k][bb];
                if (us == 0) ssum += b_out[0];
                atomicAdd(out + (size_t)(bg * 32 + bb + 8 * k) * 1024 + t, ssum);
            }
        }
    }
#undef ARR
#undef ACKP
#undef ACKD
}

extern "C" void kernel_launch(void* const* d_in, const int* in_sizes, int n_in,
                              void* d_out, int out_size, void* d_ws, size_t ws_size,
                              hipStream_t stream) {
    const float* x     = (const float*)d_in[0];
    const float* w_ih1 = (const float*)d_in[1];
    const float* w_hh1 = (const float*)d_in[2];
    const float* b_ih1 = (const float*)d_in[3];
    const float* b_hh1 = (const float*)d_in[4];
    const float* w_ih2 = (const float*)d_in[5];
    const float* w_hh2 = (const float*)d_in[6];
    const float* b_ih2 = (const float*)d_in[7];
    const float* b_hh2 = (const float*)d_in[8];
    const float* w_ih3 = (const float*)d_in[9];
    const float* w_hh3 = (const float*)d_in[10];
    const float* b_ih3 = (const float*)d_in[11];
    const float* b_hh3 = (const float*)d_in[12];
    const float* w_ih4 = (const float*)d_in[13];
    const float* w_hh4 = (const float*)d_in[14];
    const float* b_ih4 = (const float*)d_in[15];
    const float* b_hh4 = (const float*)d_in[16];
    const float* w_out = (const float*)d_in[17];
    const float* b_out = (const float*)d_in[18];

    float* ws = (float*)d_ws;
    float* wA_hh1 = ws;                  // 196608
    float* wA_ih2 = wA_hh1 + 196608;     //  98304
    float* wA_hh2 = wA_ih2 + 98304;      //  49152
    float* wA_ih3 = wA_hh2 + 49152;      //  49152
    float* wA_hh3 = wA_ih3 + 49152;      //  49152
    float* wA_ih4 = wA_hh3 + 49152;      //  98304
    float* wA_hh4 = wA_ih4 + 98304;      // 196608
    float* ex     = wA_hh4 + 196608;     // 786432 (h rings)
    int*   flags  = (int*)(ex + 786432); // 88*16 ints

    hipMemsetAsync(flags, 0, 88 * 16 * sizeof(int), stream);
    hipMemsetAsync(d_out, 0, 256 * 1024 * sizeof(float), stream);

    prep_k<<<768, 256, 0, stream>>>(w_hh1, wA_hh1, 256, 256);
    prep_k<<<384, 256, 0, stream>>>(w_ih2, wA_ih2, 128, 256);
    prep_k<<<192, 256, 0, stream>>>(w_hh2, wA_hh2, 128, 128);
    prep_k<<<192, 256, 0, stream>>>(w_ih3, wA_ih3, 128, 128);
    prep_k<<<192, 256, 0, stream>>>(w_hh3, wA_hh3, 128, 128);
    prep_k<<<384, 256, 0, stream>>>(w_ih4, wA_ih4, 256, 128);
    prep_k<<<768, 256, 0, stream>>>(w_hh4, wA_hh4, 256, 256);

    // L4 stage needs 37248 floats = 148992 B of dynamic LDS (>64KB default cap)
    const int dyn_lds = 37248 * (int)sizeof(float);
    hipFuncSetAttribute((const void*)gru_pipe_kernel,
                        hipFuncAttributeMaxDynamicSharedMemorySize, dyn_lds);

    gru_pipe_kernel<<<256, 256, dyn_lds, stream>>>(
        x, w_ih1, b_ih1, b_hh1, b_ih2, b_hh2, b_ih3, b_hh3, b_ih4, b_hh4,
        wA_hh1, wA_ih2, wA_hh2, wA_ih3, wA_hh3, wA_ih4, wA_hh4,
        w_out, b_out, flags, ex, (float*)d_out);
}